// Round 5
// baseline (2518.706 us; speedup 1.0000x reference)
//
#include <hip/hip_runtime.h>
#include <hip/hip_fp16.h>
#include <math.h>

// Liquid-network recurrence, one batch row per CU (grid=256, block=512).
// Thread t = 8g+p: computes outputs [8g,8g+8) over k-slice [64p,64p+64),
// then a 3-round DPP transpose-reduce lands full rec[t] on thread t.
// Weight pairs per thread: 32 k2 x 8 outputs = 256 u32.
//   k2  0..15 -> VGPR (128 u32, direct v_dot2 src)
//   k2 16..23 -> AGPR (64 u32, v_accvgpr_read + v_dot2)
//   k2 24..31 -> LDS  (16 b128 slots/thread/step)
// h: f16, double-buffered in LDS, XOR-swizzled chunks (conflict-free).

#define HID    512
#define NSTEP  1024
#define BLK    512
#define KV     16
#define KA     8

// dynamic LDS layout (bytes)
#define OFF_WLDS  0               // 16 slots x 512 threads x uint4 = 131072
#define OFF_HB0   131072          // 64 x uint4 = 1024
#define OFF_HB1   132096          // 64 x uint4 = 1024
#define OFF_XLS   133120          // 2048 f32   = 8192
#define OFF_RED   141312          // 16 f32     = 64
#define OFF_HNA   141376          // 512 f32    = 2048
#define OFF_PSUM  143424          // 160 f32    = 640
#define SMEM_BYTES 144064

typedef _Float16 half2_t __attribute__((ext_vector_type(2)));

__device__ __forceinline__ float dot2f(float acc, uint32_t w, uint32_t h) {
#if __has_builtin(__builtin_amdgcn_fdot2)
    return __builtin_amdgcn_fdot2(__builtin_bit_cast(half2_t, w),
                                  __builtin_bit_cast(half2_t, h), acc, false);
#else
    asm("v_dot2_f32_f16 %0, %1, %2, %0" : "+v"(acc) : "v"(w), "v"(h));
    return acc;
#endif
}

// AGPR-resident weight: explicit move to VGPR (full-rate VALU), then dot2.
// (VOP3P v_dot2 cannot encode an AGPR source on gfx950.)
__device__ __forceinline__ void dot2a(float& acc, const uint32_t& w_a, uint32_t h) {
    uint32_t tmp;
    asm("v_accvgpr_read_b32 %0, %1" : "=v"(tmp) : "a"(w_a));
    acc = dot2f(acc, tmp, h);
}

template <int CTRL>
__device__ __forceinline__ float dpp_f(float v) {
    int r = __builtin_amdgcn_update_dpp(0, __builtin_bit_cast(int, v),
                                        CTRL, 0xF, 0xF, true);
    return __builtin_bit_cast(float, r);
}
// DPP controls: 0xB1 quad_perm[1,0,3,2] (xor1), 0x4E quad_perm[2,3,0,1] (xor2),
// 0x1B quad_perm[3,2,1,0] (xor3/mirror4), 0x141 row_half_mirror (xor7 in 8),
// 0x140 row_mirror (xor15 in 16).

__device__ __forceinline__ float swz16_f(float v) {
    int r = __builtin_amdgcn_ds_swizzle(__builtin_bit_cast(int, v), 0x401F); // xor16
    return __builtin_bit_cast(float, r);
}

__device__ __forceinline__ uint32_t pack2h(float a, float b) {
    __half2 h2 = __floats2half2_rn(a, b);   // a -> low 16 bits
    union { __half2 h; uint32_t u; } cv; cv.h = h2;
    return cv.u;
}

__device__ __forceinline__ float tanh_fast(float y) {
    float e = __expf(2.0f * y);
    return 1.0f - 2.0f * __builtin_amdgcn_rcpf(e + 1.0f);
}

extern "C" __global__ void __launch_bounds__(BLK, 2)
__attribute__((amdgpu_waves_per_eu(2, 2)))
liquid_kernel(const float* __restrict__ x, const float* __restrict__ ctx,
              const float* __restrict__ ce_w1, const float* __restrict__ ce_b1,
              const float* __restrict__ ce_w2, const float* __restrict__ ce_b2,
              const float* __restrict__ in_w, const float* __restrict__ in_b,
              const float* __restrict__ rec_w, const float* __restrict__ tau,
              const float* __restrict__ intra_g, const float* __restrict__ intra_b,
              const float* __restrict__ norm_g, const float* __restrict__ norm_b,
              const float* __restrict__ head_w, const float* __restrict__ head_b,
              float* __restrict__ out)
{
    extern __shared__ char smem[];
    uint4* wlds4 = (uint4*)(smem + OFF_WLDS);
    float* xls   = (float*)(smem + OFF_XLS);
    float* redS  = (float*)(smem + OFF_RED);
    float* hnA   = (float*)(smem + OFF_HNA);
    float* psum  = (float*)(smem + OFF_PSUM);
    __half* hbase0 = (__half*)(smem + OFF_HB0);
    __half* hbase1 = (__half*)(smem + OFF_HB1);

    const int b  = blockIdx.x;
    const int t  = threadIdx.x;
    const int p  = t & 7;          // k-slice
    const int g  = t >> 3;         // output group
    const int wv = t >> 6;         // wave id
    const int ln = t & 63;

    // ---- stage x[b] (1024 x 2 fp32 = 8 KB), coalesced ----
    const float* xb = x + (size_t)b * (NSTEP * 2);
    #pragma unroll
    for (int q = 0; q < 4; ++q) xls[t + q * BLK] = xb[t + q * BLK];

    // ---- per-thread params (column j == t) ----
    const float g_j  = intra_g[t];
    const float bb_j = intra_b[t];
    const float iw0  = in_w[t];
    const float iw1  = in_w[HID + t];
    const float ib_j = in_b[t];
    const float tj   = tau[t];
    const float sp   = (tj > 30.f) ? tj : log1pf(__expf(tj));
    const float itau = 1.0f / sp;

    // ---- h0 = tanh(relu(ctx@ce_w1+b1)@ce_w2+b2) ----
    float t1[32];
    #pragma unroll
    for (int k = 0; k < 32; ++k) {
        float s = ce_b1[k];
        #pragma unroll
        for (int i = 0; i < 6; ++i) s += ctx[b * 6 + i] * ce_w1[i * 32 + k];
        t1[k] = fmaxf(s, 0.f);
    }
    float s0 = ce_b2[t];
    #pragma unroll
    for (int k = 0; k < 32; ++k) s0 += t1[k] * ce_w2[k * HID + t];
    float h = tanh_fast(s0);

    // ---- weights: pair k2 covers rows 64p+2k2, 64p+2k2+1; cols 8g..8g+7 ----
    uint32_t wv_[KV * 8];          // VGPR-resident
    uint32_t wa_[KA * 8];          // AGPR-resident (forced by "a" constraint at use)
    #pragma unroll
    for (int k2 = 0; k2 < KV; ++k2) {
        const size_t r0 = (size_t)(64 * p + 2 * k2) * HID + 8 * g;
        #pragma unroll
        for (int jj = 0; jj < 8; ++jj)
            wv_[k2 * 8 + jj] = pack2h(rec_w[r0 + jj], rec_w[r0 + HID + jj]);
    }
    #pragma unroll
    for (int k2 = KV; k2 < KV + KA; ++k2) {
        const size_t r0 = (size_t)(64 * p + 2 * k2) * HID + 8 * g;
        #pragma unroll
        for (int jj = 0; jj < 8; ++jj)
            wa_[(k2 - KV) * 8 + jj] = pack2h(rec_w[r0 + jj], rec_w[r0 + HID + jj]);
    }
    #pragma unroll
    for (int k2 = KV + KA; k2 < 32; ++k2) {
        const size_t r0 = (size_t)(64 * p + 2 * k2) * HID + 8 * g;
        uint4 w0, w1;
        w0.x = pack2h(rec_w[r0 + 0], rec_w[r0 + HID + 0]);
        w0.y = pack2h(rec_w[r0 + 1], rec_w[r0 + HID + 1]);
        w0.z = pack2h(rec_w[r0 + 2], rec_w[r0 + HID + 2]);
        w0.w = pack2h(rec_w[r0 + 3], rec_w[r0 + HID + 3]);
        w1.x = pack2h(rec_w[r0 + 4], rec_w[r0 + HID + 4]);
        w1.y = pack2h(rec_w[r0 + 5], rec_w[r0 + HID + 5]);
        w1.z = pack2h(rec_w[r0 + 6], rec_w[r0 + HID + 6]);
        w1.w = pack2h(rec_w[r0 + 7], rec_w[r0 + HID + 7]);
        const int s = (k2 - (KV + KA)) * 2;
        wlds4[(s + 0) * BLK + t] = w0;
        wlds4[(s + 1) * BLK + t] = w1;
    }

    // ---- h write offset (XOR-swizzled chunks): pair P = t>>1 ----
    int hOff;
    {
        const int P = t >> 1, pw = P >> 5, kq = (P >> 2) & 7, e = P & 3;
        hOff = (8 * kq + (pw ^ kq)) * 8 + e * 2 + (t & 1);
    }
    hbase0[hOff] = __float2half_rn(h);
    __syncthreads();

    const uint4* hR = (const uint4*)hbase0;
    __half*      hW = hbase1;

    for (int step = 0; step < NSTEP; ++step) {
        float acc[8] = {0.f, 0.f, 0.f, 0.f, 0.f, 0.f, 0.f, 0.f};

        // kq 0..3: VGPR weights (k2 0..15)
        #pragma unroll
        for (int kq = 0; kq < KV / 4; ++kq) {
            uint4 hv = hR[8 * kq + (p ^ kq)];
            #pragma unroll
            for (int e = 0; e < 4; ++e) {
                const int k2 = 4 * kq + e;
                const uint32_t hp = (e == 0) ? hv.x : (e == 1) ? hv.y : (e == 2) ? hv.z : hv.w;
                #pragma unroll
                for (int jj = 0; jj < 8; ++jj)
                    acc[jj] = dot2f(acc[jj], wv_[k2 * 8 + jj], hp);
            }
        }
        // kq 4..5: AGPR weights (k2 16..23), accvgpr_read + dot2
        #pragma unroll
        for (int kq = KV / 4; kq < (KV + KA) / 4; ++kq) {
            uint4 hv = hR[8 * kq + (p ^ kq)];
            #pragma unroll
            for (int e = 0; e < 4; ++e) {
                const int ka = 4 * kq + e - KV;
                const uint32_t hp = (e == 0) ? hv.x : (e == 1) ? hv.y : (e == 2) ? hv.z : hv.w;
                #pragma unroll
                for (int jj = 0; jj < 8; ++jj)
                    dot2a(acc[jj], wa_[ka * 8 + jj], hp);
            }
        }
        // kq 6..7: LDS weights (k2 24..31)
        #pragma unroll
        for (int kq = (KV + KA) / 4; kq < 8; ++kq) {
            uint4 hv = hR[8 * kq + (p ^ kq)];
            #pragma unroll
            for (int e = 0; e < 4; ++e) {
                const int k2 = 4 * kq + e;
                const int s  = (k2 - (KV + KA)) * 2;
                uint4 w0 = wlds4[(s + 0) * BLK + t];
                uint4 w1 = wlds4[(s + 1) * BLK + t];
                const uint32_t hp = (e == 0) ? hv.x : (e == 1) ? hv.y : (e == 2) ? hv.z : hv.w;
                acc[0] = dot2f(acc[0], w0.x, hp); acc[1] = dot2f(acc[1], w0.y, hp);
                acc[2] = dot2f(acc[2], w0.z, hp); acc[3] = dot2f(acc[3], w0.w, hp);
                acc[4] = dot2f(acc[4], w1.x, hp); acc[5] = dot2f(acc[5], w1.y, hp);
                acc[6] = dot2f(acc[6], w1.z, hp); acc[7] = dot2f(acc[7], w1.w, hp);
            }
        }

        // DPP transpose-reduce across p (3 rounds): thread t ends with rec[t]
        float b4[4];
        {
            const bool hi = (p & 4);
            #pragma unroll
            for (int i = 0; i < 4; ++i) {
                float keep = hi ? acc[i + 4] : acc[i];
                float send = hi ? acc[i]     : acc[i + 4];
                b4[i] = keep + dpp_f<0x141>(send);      // row_half_mirror (xor7 in 8)
            }
        }
        float c2[2];
        {
            const bool hi = (p & 2);
            #pragma unroll
            for (int i = 0; i < 2; ++i) {
                float keep = hi ? b4[i + 2] : b4[i];
                float send = hi ? b4[i]     : b4[i + 2];
                c2[i] = keep + dpp_f<0x1B>(send);       // quad mirror (xor3)
            }
        }
        float rec;
        {
            const bool hi = (p & 1);
            float keep = hi ? c2[1] : c2[0];
            float send = hi ? c2[0] : c2[1];
            rec = keep + dpp_f<0xB1>(send);             // xor1
        }

        float2 xv = ((const float2*)xls)[step];
        float v = fmaf(xv.x, iw0, fmaf(xv.y, iw1, ib_j + rec));

        // wave LN reduce: 4 DPP levels + xor16 swizzle + xor32 shuffle
        float s1 = v, sq = v * v;
        s1 += dpp_f<0xB1>(s1);  sq += dpp_f<0xB1>(sq);
        s1 += dpp_f<0x4E>(s1);  sq += dpp_f<0x4E>(sq);
        s1 += dpp_f<0x141>(s1); sq += dpp_f<0x141>(sq);
        s1 += dpp_f<0x140>(s1); sq += dpp_f<0x140>(sq);
        s1 += swz16_f(s1);      sq += swz16_f(sq);
        s1 += __shfl_xor(s1, 32); sq += __shfl_xor(sq, 32);

        if (ln == 0) { redS[wv] = s1; redS[8 + wv] = sq; }
        __syncthreads();
        const float4* rp = (const float4*)redS;
        float4 r0 = rp[0], r1 = rp[1], r2 = rp[2], r3 = rp[3];
        float S1 = ((r0.x + r0.y) + (r0.z + r0.w)) + ((r1.x + r1.y) + (r1.z + r1.w));
        float S2 = ((r2.x + r2.y) + (r2.z + r2.w)) + ((r3.x + r3.y) + (r3.z + r3.w));
        float mu  = S1 * (1.0f / HID);
        float var = S2 * (1.0f / HID) - mu * mu;
        float rs  = rsqrtf(var + 1e-5f);
        float f   = tanh_fast((v - mu) * rs * g_j + bb_j);

        h = h + (f - h * itau) * 0.1f;
        h = fminf(fmaxf(h, -10.f), 10.f);
        hW[hOff] = __float2half_rn(h);
        __syncthreads();
        const uint4* tmp = hR; hR = (const uint4*)hW; hW = (__half*)tmp;
    }

    // ---- final layernorm ----
    float s1 = h, sq = h * h;
    s1 += dpp_f<0xB1>(s1);  sq += dpp_f<0xB1>(sq);
    s1 += dpp_f<0x4E>(s1);  sq += dpp_f<0x4E>(sq);
    s1 += dpp_f<0x141>(s1); sq += dpp_f<0x141>(sq);
    s1 += dpp_f<0x140>(s1); sq += dpp_f<0x140>(sq);
    s1 += swz16_f(s1);      sq += swz16_f(sq);
    s1 += __shfl_xor(s1, 32); sq += __shfl_xor(sq, 32);
    if (ln == 0) { redS[wv] = s1; redS[8 + wv] = sq; }
    __syncthreads();
    {
        const float4* rp = (const float4*)redS;
        float4 r0 = rp[0], r1 = rp[1], r2 = rp[2], r3 = rp[3];
        float S1 = ((r0.x + r0.y) + (r0.z + r0.w)) + ((r1.x + r1.y) + (r1.z + r1.w));
        float S2 = ((r2.x + r2.y) + (r2.z + r2.w)) + ((r3.x + r3.y) + (r3.z + r3.w));
        float mu  = S1 * (1.0f / HID);
        float var = S2 * (1.0f / HID) - mu * mu;
        float rs  = rsqrtf(var + 1e-5f);
        hnA[t] = (h - mu) * rs * norm_g[t] + norm_b[t];
    }
    __syncthreads();

    // ---- heads: out[b, a] = hn . head_w[:, a] + head_b[a] ----
    if (t < 160) {
        int a = t >> 3, part = t & 7;
        float s = 0.f;
        #pragma unroll 8
        for (int q = 0; q < 64; ++q) {
            int row = part * 64 + q;
            s += hnA[row] * head_w[row * 20 + a];
        }
        psum[a * 8 + part] = s;
    }
    __syncthreads();
    if (t < 20) {
        float s = head_b[t];
        #pragma unroll
        for (int q = 0; q < 8; ++q) s += psum[t * 8 + q];
        out[b * 20 + t] = s;
    }
}

extern "C" void kernel_launch(void* const* d_in, const int* in_sizes, int n_in,
                              void* d_out, int out_size, void* d_ws, size_t ws_size,
                              hipStream_t stream) {
    const float* x       = (const float*)d_in[0];
    const float* ctx     = (const float*)d_in[1];
    const float* ce_w1   = (const float*)d_in[2];
    const float* ce_b1   = (const float*)d_in[3];
    const float* ce_w2   = (const float*)d_in[4];
    const float* ce_b2   = (const float*)d_in[5];
    const float* in_w    = (const float*)d_in[6];
    const float* in_b    = (const float*)d_in[7];
    const float* rec_w   = (const float*)d_in[8];
    const float* tau     = (const float*)d_in[9];
    const float* intra_g = (const float*)d_in[10];
    const float* intra_b = (const float*)d_in[11];
    const float* norm_g  = (const float*)d_in[12];
    const float* norm_b  = (const float*)d_in[13];
    const float* head_w  = (const float*)d_in[14];
    const float* head_b  = (const float*)d_in[15];
    float* outp = (float*)d_out;

    (void)d_ws; (void)ws_size; (void)n_in; (void)in_sizes; (void)out_size;

    // opt-in to >64KB dynamic LDS (160 KB/CU on gfx950); host-side, capture-safe
    hipFuncSetAttribute((const void*)liquid_kernel,
                        hipFuncAttributeMaxDynamicSharedMemorySize, SMEM_BYTES);

    liquid_kernel<<<dim3(256), dim3(BLK), SMEM_BYTES, stream>>>(
        x, ctx, ce_w1, ce_b1, ce_w2, ce_b2, in_w, in_b, rec_w, tau,
        intra_g, intra_b, norm_g, norm_b, head_w, head_b, outp);
}